// Round 1
// baseline (6950.658 us; speedup 1.0000x reference)
//
#include <hip/hip_runtime.h>

typedef __bf16 bf16_t;
typedef __bf16 bf16x8 __attribute__((ext_vector_type(8)));
typedef __bf16 bf16x4 __attribute__((ext_vector_type(4)));
typedef float f32x16 __attribute__((ext_vector_type(16)));

// Problem dims: B=32, S=512, D=512, H=1024, 4H=4096
// ws layout (bytes)
#define SZ_XBF    (16384ull*512*2)      // x bf16, rows permuted to t*32+b
#define SZ_WIH    (4096ull*512*2)
#define SZ_WHH    (4096ull*1024*2)
#define SZ_XPROJ  (16384ull*4096*2)     // [t*32+b][4096] bf16
#define SZ_HTR    (513ull*32*1024*2)    // h trace bf16, slot 0 = h0
#define OFF_XBF   (0ull)
#define OFF_WIH   (OFF_XBF + SZ_XBF)
#define OFF_WHH   (OFF_WIH + SZ_WIH)
#define OFF_XPROJ (OFF_WHH + SZ_WHH)
#define OFF_HTR   (OFF_XPROJ + SZ_XPROJ)
#define OFF_FLAGS (OFF_HTR + SZ_HTR)    // 64 flags, one per 64B

// ---------------------------------------------------------------------------
// Kernel 1: convert inputs to bf16 (x permuted), init h-trace slot 0, zero flags
// ---------------------------------------------------------------------------
__global__ __launch_bounds__(256) void convert_pack(
    const float* __restrict__ x, const float* __restrict__ h0,
    const float* __restrict__ Wih, const float* __restrict__ Whh,
    bf16_t* __restrict__ xbf, bf16_t* __restrict__ wihbf,
    bf16_t* __restrict__ whhbf, bf16_t* __restrict__ htr,
    int* __restrict__ flags)
{
  long long v = (long long)blockIdx.x * 256 + threadIdx.x;
  if (v < 2097152LL) {                       // x: 8388608 floats, 4 per thread
    long long fi = v * 4;
    int b = (int)(fi >> 18);                 // 512*512 = 2^18
    int rem = (int)(fi & 0x3FFFF);
    int s = rem >> 9, d = rem & 511;
    float4 f = *(const float4*)(x + fi);
    bf16x4 o; o.x = (bf16_t)f.x; o.y = (bf16_t)f.y; o.z = (bf16_t)f.z; o.w = (bf16_t)f.w;
    *(bf16x4*)(xbf + ((long long)(s*32 + b)*512 + d)) = o;
  } else if (v < 2621440LL) {                // W_ih: 2097152 floats
    long long fi = (v - 2097152LL) * 4;
    float4 f = *(const float4*)(Wih + fi);
    bf16x4 o; o.x = (bf16_t)f.x; o.y = (bf16_t)f.y; o.z = (bf16_t)f.z; o.w = (bf16_t)f.w;
    *(bf16x4*)(wihbf + fi) = o;
  } else if (v < 3670016LL) {                // W_hh: 4194304 floats
    long long fi = (v - 2621440LL) * 4;
    float4 f = *(const float4*)(Whh + fi);
    bf16x4 o; o.x = (bf16_t)f.x; o.y = (bf16_t)f.y; o.z = (bf16_t)f.z; o.w = (bf16_t)f.w;
    *(bf16x4*)(whhbf + fi) = o;
  } else if (v < 3678208LL) {                // h0: 32768 floats -> htr slot 0
    long long fi = (v - 3670016LL) * 4;
    float4 f = *(const float4*)(h0 + fi);
    bf16x4 o; o.x = (bf16_t)f.x; o.y = (bf16_t)f.y; o.z = (bf16_t)f.z; o.w = (bf16_t)f.w;
    *(bf16x4*)(htr + fi) = o;
  } else if (v < 3678464LL) {                // flags: 1024 ints -> 0
    int i = (int)(v - 3678208LL) * 4;
    *(int4*)(flags + i) = make_int4(0, 0, 0, 0);
  }
}

// ---------------------------------------------------------------------------
// Kernel 2: x_proj = X(bf16, rows t*32+b) @ W_ih^T + b_ih + b_hh  -> bf16
// 128x128 block tile, BK=64, 4 waves (2x2 of 64x64), 32x32x16 MFMA.
// LDS tiles stored XOR-swizzled in 16B blocks: slot(r,blk) = r*8 + (blk ^ (r&7))
// ---------------------------------------------------------------------------
__global__ __launch_bounds__(256) void xproj_gemm(
    const bf16_t* __restrict__ Xb, const bf16_t* __restrict__ Wb,
    const float* __restrict__ bih, const float* __restrict__ bhh,
    bf16_t* __restrict__ XP)
{
  __shared__ bf16_t As[128*64];
  __shared__ bf16_t Bs[128*64];
  const int tid = threadIdx.x;
  const int lane = tid & 63, wave = tid >> 6;
  const int mhalf = wave & 1, nhalf = wave >> 1;
  const int l31 = lane & 31, khi = lane >> 5;
  const int m0 = blockIdx.x * 128, n0 = blockIdx.y * 128;

  f32x16 acc[2][2] = {};

  for (int kb = 0; kb < 8; ++kb) {
    const int k0 = kb * 64;
    __syncthreads();
    // stage A,B: 1024 16B-chunks each, swizzled
#pragma unroll
    for (int j = 0; j < 4; ++j) {
      int cid = j * 256 + tid;
      int r = cid >> 3, bs = cid & 7;
      int bb = bs ^ (r & 7);
      *(bf16x8*)(As + cid * 8) = *(const bf16x8*)(Xb + (long long)(m0 + r) * 512 + k0 + bb * 8);
      *(bf16x8*)(Bs + cid * 8) = *(const bf16x8*)(Wb + (long long)(n0 + r) * 512 + k0 + bb * 8);
    }
    __syncthreads();
#pragma unroll
    for (int ks = 0; ks < 4; ++ks) {
      int blk = ks * 2 + khi;
      bf16x8 af[2], bfr[2];
#pragma unroll
      for (int mt = 0; mt < 2; ++mt) {
        int r = mhalf * 64 + mt * 32 + l31;
        af[mt] = *(const bf16x8*)(As + (r * 8 + (blk ^ (r & 7))) * 8);
      }
#pragma unroll
      for (int nt = 0; nt < 2; ++nt) {
        int r = nhalf * 64 + nt * 32 + l31;
        bfr[nt] = *(const bf16x8*)(Bs + (r * 8 + (blk ^ (r & 7))) * 8);
      }
#pragma unroll
      for (int mt = 0; mt < 2; ++mt)
#pragma unroll
        for (int nt = 0; nt < 2; ++nt)
          acc[mt][nt] = __builtin_amdgcn_mfma_f32_32x32x16_bf16(af[mt], bfr[nt], acc[mt][nt], 0, 0, 0);
    }
  }
  // epilogue: C layout col=lane&31, row=(r&3)+8*(r>>2)+4*(lane>>5)
#pragma unroll
  for (int nt = 0; nt < 2; ++nt) {
    int ng = n0 + nhalf * 64 + nt * 32 + l31;
    float bias = bih[ng] + bhh[ng];
#pragma unroll
    for (int mt = 0; mt < 2; ++mt) {
#pragma unroll
      for (int r = 0; r < 16; ++r) {
        int row = (r & 3) + 8 * (r >> 2) + 4 * khi;
        long long mg = m0 + mhalf * 64 + mt * 32 + row;   // = t*32 + b
        XP[mg * 4096 + ng] = (bf16_t)(acc[mt][nt][r] + bias);
      }
    }
  }
}

// ---------------------------------------------------------------------------
// Kernel 3: persistent LSTM recurrence. 64 WGs x 256 threads; WG owns 16 h-cols
// (64 gate rows). W_hh slice lives in registers (32 x bf16x8 per lane).
// Per-step sync: per-WG monotonic flag (release store / acquire poll).
// ---------------------------------------------------------------------------
__device__ __forceinline__ float sigf(float x) { return 1.0f / (1.0f + __expf(-x)); }
__device__ __forceinline__ float tanhfast(float x) {
  float e = __expf(-2.0f * fabsf(x));
  float t = (1.0f - e) / (1.0f + e);
  return copysignf(t, x);
}

__global__ __launch_bounds__(256, 1) void lstm_rec(
    const bf16_t* __restrict__ Whh_b, const bf16_t* __restrict__ XP,
    const float* __restrict__ c0, float* __restrict__ OUT,
    bf16_t* __restrict__ HTR, int* flags)
{
  const int tid = threadIdx.x;
  const int lane = tid & 63, wave = tid >> 6;
  const int ntile = wave & 1, khalf = wave >> 1;   // 2 N-tiles x 2 K-halves
  const int wg = blockIdx.x;
  const int l31 = lane & 31, khi = lane >> 5;

  // --- preload W_hh fragments into registers ---
  // local gate col nl in [0,64): [i(16) | f(16) | g(16) | o(16)]
  const int nl = ntile * 32 + l31;
  const int grow = (nl >> 4) * 1024 + wg * 16 + (nl & 15);  // W_hh row
  const int kbase = khalf * 512 + khi * 8;
  bf16x8 wreg[32];
#pragma unroll
  for (int s = 0; s < 32; ++s)
    wreg[s] = *(const bf16x8*)(Whh_b + (long long)grow * 1024 + kbase + s * 16);

  __shared__ float gL[2][32][65];   // [khalf][m][n_local], padded
  __shared__ float cS[32][18];      // c state fp32, padded
  const int m_e = tid >> 3;
  const int jp = (tid & 7) * 2;
  cS[m_e][jp]     = c0[m_e * 1024 + wg * 16 + jp];
  cS[m_e][jp + 1] = c0[m_e * 1024 + wg * 16 + jp + 1];
  __syncthreads();

  for (int t = 0; t < 512; ++t) {
    // prefetch this step's x_proj contributions (independent of the flag wait)
    const bf16_t* xpb = XP + ((long long)t * 32 + m_e) * 4096 + wg * 16 + jp;
    float xp[4][2];
#pragma unroll
    for (int g = 0; g < 4; ++g) {
      xp[g][0] = (float)xpb[g * 1024];
      xp[g][1] = (float)xpb[g * 1024 + 1];
    }

    // wait until every WG has published h_t
    if (tid < 64) {
      while (__hip_atomic_load(&flags[tid * 16], __ATOMIC_ACQUIRE,
                               __HIP_MEMORY_SCOPE_AGENT) < t)
        __builtin_amdgcn_s_sleep(1);
    }
    __syncthreads();

    // gates partial = W_slice . h_t   (A: h rows m=lane&31, k contiguous)
    const bf16_t* hrow = HTR + (long long)t * 32768 + (long long)l31 * 1024 + kbase;
    f32x16 acc = {};
#pragma unroll
    for (int s = 0; s < 32; ++s) {
      bf16x8 a = *(const bf16x8*)(hrow + s * 16);
      acc = __builtin_amdgcn_mfma_f32_32x32x16_bf16(a, wreg[s], acc, 0, 0, 0);
    }
#pragma unroll
    for (int r = 0; r < 16; ++r) {
      int mm = (r & 3) + 8 * (r >> 2) + 4 * khi;
      gL[khalf][mm][nl] = acc[r];
    }
    __syncthreads();

    // elementwise LSTM cell for (m_e, jp..jp+1)
#pragma unroll
    for (int e = 0; e < 2; ++e) {
      int j = jp + e;
      float ir  = gL[0][m_e][j]      + gL[1][m_e][j]      + xp[0][e];
      float fr  = gL[0][m_e][16 + j] + gL[1][m_e][16 + j] + xp[1][e];
      float gr  = gL[0][m_e][32 + j] + gL[1][m_e][32 + j] + xp[2][e];
      float orr = gL[0][m_e][48 + j] + gL[1][m_e][48 + j] + xp[3][e];
      float iv = sigf(ir), fv = sigf(fr), gv = tanhfast(gr), ov = sigf(orr);
      float c = fv * cS[m_e][j] + iv * gv;
      cS[m_e][j] = c;
      float hv = ov * tanhfast(c);
      OUT[((long long)m_e * 512 + t) * 1024 + wg * 16 + j] = hv;
      HTR[(long long)(t + 1) * 32768 + (long long)m_e * 1024 + wg * 16 + j] = (bf16_t)hv;
    }
    __threadfence();          // drain h stores to device scope
    __syncthreads();
    if (tid == 0)
      __hip_atomic_store(&flags[wg * 16], t + 1, __ATOMIC_RELEASE,
                         __HIP_MEMORY_SCOPE_AGENT);
  }
}

// ---------------------------------------------------------------------------
extern "C" void kernel_launch(void* const* d_in, const int* in_sizes, int n_in,
                              void* d_out, int out_size, void* d_ws, size_t ws_size,
                              hipStream_t stream)
{
  const float* x   = (const float*)d_in[0];
  const float* h0  = (const float*)d_in[1];
  const float* c0  = (const float*)d_in[2];
  const float* Wih = (const float*)d_in[3];
  const float* Whh = (const float*)d_in[4];
  const float* bih = (const float*)d_in[5];
  const float* bhh = (const float*)d_in[6];
  float* out = (float*)d_out;

  char* ws = (char*)d_ws;
  bf16_t* xbf   = (bf16_t*)(ws + OFF_XBF);
  bf16_t* wihbf = (bf16_t*)(ws + OFF_WIH);
  bf16_t* whhbf = (bf16_t*)(ws + OFF_WHH);
  bf16_t* xproj = (bf16_t*)(ws + OFF_XPROJ);
  bf16_t* htr   = (bf16_t*)(ws + OFF_HTR);
  int* flags    = (int*)(ws + OFF_FLAGS);

  convert_pack<<<14369, 256, 0, stream>>>(x, h0, Wih, Whh, xbf, wihbf, whhbf, htr, flags);
  xproj_gemm<<<dim3(128, 32), 256, 0, stream>>>(xbf, wihbf, bih, bhh, xproj);
  lstm_rec<<<64, 256, 0, stream>>>(whhbf, xproj, c0, out, htr, flags);
}

// Round 2
// 3552.737 us; speedup vs baseline: 1.9564x; 1.9564x over previous
//
#include <hip/hip_runtime.h>

typedef __bf16 bf16_t;
typedef __bf16 bf16x8 __attribute__((ext_vector_type(8)));
typedef __bf16 bf16x4 __attribute__((ext_vector_type(4)));
typedef __bf16 bf16x2 __attribute__((ext_vector_type(2)));
typedef float f32x16 __attribute__((ext_vector_type(16)));

// Problem dims: B=32, S=512, D=512, H=1024, 4H=4096
// ws layout (bytes)
#define SZ_XBF    (16384ull*512*2)      // x bf16, rows permuted to t*32+b
#define SZ_WIH    (4096ull*512*2)
#define SZ_WHH    (4096ull*1024*2)
#define SZ_XPROJ  (16384ull*4096*2)     // [t*32+b][4096] bf16
#define SZ_HTR    (513ull*32*1024*2)    // h trace bf16, slot 0 = h0
#define OFF_XBF   (0ull)
#define OFF_WIH   (OFF_XBF + SZ_XBF)
#define OFF_WHH   (OFF_WIH + SZ_WIH)
#define OFF_XPROJ (OFF_WHH + SZ_WHH)
#define OFF_HTR   (OFF_XPROJ + SZ_XPROJ)
#define OFF_FLAGS (OFF_HTR + SZ_HTR)    // 64 flags, one per 64B

// ---------------------------------------------------------------------------
// Kernel 1: convert inputs to bf16 (x permuted), init h-trace slot 0, zero flags
// ---------------------------------------------------------------------------
__global__ __launch_bounds__(256) void convert_pack(
    const float* __restrict__ x, const float* __restrict__ h0,
    const float* __restrict__ Wih, const float* __restrict__ Whh,
    bf16_t* __restrict__ xbf, bf16_t* __restrict__ wihbf,
    bf16_t* __restrict__ whhbf, bf16_t* __restrict__ htr,
    int* __restrict__ flags)
{
  long long v = (long long)blockIdx.x * 256 + threadIdx.x;
  if (v < 2097152LL) {                       // x: 8388608 floats, 4 per thread
    long long fi = v * 4;
    int b = (int)(fi >> 18);                 // 512*512 = 2^18
    int rem = (int)(fi & 0x3FFFF);
    int s = rem >> 9, d = rem & 511;
    float4 f = *(const float4*)(x + fi);
    bf16x4 o; o.x = (bf16_t)f.x; o.y = (bf16_t)f.y; o.z = (bf16_t)f.z; o.w = (bf16_t)f.w;
    *(bf16x4*)(xbf + ((long long)(s*32 + b)*512 + d)) = o;
  } else if (v < 2621440LL) {                // W_ih: 2097152 floats
    long long fi = (v - 2097152LL) * 4;
    float4 f = *(const float4*)(Wih + fi);
    bf16x4 o; o.x = (bf16_t)f.x; o.y = (bf16_t)f.y; o.z = (bf16_t)f.z; o.w = (bf16_t)f.w;
    *(bf16x4*)(wihbf + fi) = o;
  } else if (v < 3670016LL) {                // W_hh: 4194304 floats
    long long fi = (v - 2621440LL) * 4;
    float4 f = *(const float4*)(Whh + fi);
    bf16x4 o; o.x = (bf16_t)f.x; o.y = (bf16_t)f.y; o.z = (bf16_t)f.z; o.w = (bf16_t)f.w;
    *(bf16x4*)(whhbf + fi) = o;
  } else if (v < 3678208LL) {                // h0: 32768 floats -> htr slot 0
    long long fi = (v - 3670016LL) * 4;
    float4 f = *(const float4*)(h0 + fi);
    bf16x4 o; o.x = (bf16_t)f.x; o.y = (bf16_t)f.y; o.z = (bf16_t)f.z; o.w = (bf16_t)f.w;
    *(bf16x4*)(htr + fi) = o;
  } else if (v < 3678464LL) {                // flags: 1024 ints -> 0
    int i = (int)(v - 3678208LL) * 4;
    *(int4*)(flags + i) = make_int4(0, 0, 0, 0);
  }
}

// ---------------------------------------------------------------------------
// Kernel 2: x_proj = X(bf16, rows t*32+b) @ W_ih^T + b_ih + b_hh  -> bf16
// ---------------------------------------------------------------------------
__global__ __launch_bounds__(256) void xproj_gemm(
    const bf16_t* __restrict__ Xb, const bf16_t* __restrict__ Wb,
    const float* __restrict__ bih, const float* __restrict__ bhh,
    bf16_t* __restrict__ XP)
{
  __shared__ bf16_t As[128*64];
  __shared__ bf16_t Bs[128*64];
  const int tid = threadIdx.x;
  const int lane = tid & 63, wave = tid >> 6;
  const int mhalf = wave & 1, nhalf = wave >> 1;
  const int l31 = lane & 31, khi = lane >> 5;
  const int m0 = blockIdx.x * 128, n0 = blockIdx.y * 128;

  f32x16 acc[2][2] = {};

  for (int kb = 0; kb < 8; ++kb) {
    const int k0 = kb * 64;
    __syncthreads();
#pragma unroll
    for (int j = 0; j < 4; ++j) {
      int cid = j * 256 + tid;
      int r = cid >> 3, bs = cid & 7;
      int bb = bs ^ (r & 7);
      *(bf16x8*)(As + cid * 8) = *(const bf16x8*)(Xb + (long long)(m0 + r) * 512 + k0 + bb * 8);
      *(bf16x8*)(Bs + cid * 8) = *(const bf16x8*)(Wb + (long long)(n0 + r) * 512 + k0 + bb * 8);
    }
    __syncthreads();
#pragma unroll
    for (int ks = 0; ks < 4; ++ks) {
      int blk = ks * 2 + khi;
      bf16x8 af[2], bfr[2];
#pragma unroll
      for (int mt = 0; mt < 2; ++mt) {
        int r = mhalf * 64 + mt * 32 + l31;
        af[mt] = *(const bf16x8*)(As + (r * 8 + (blk ^ (r & 7))) * 8);
      }
#pragma unroll
      for (int nt = 0; nt < 2; ++nt) {
        int r = nhalf * 64 + nt * 32 + l31;
        bfr[nt] = *(const bf16x8*)(Bs + (r * 8 + (blk ^ (r & 7))) * 8);
      }
#pragma unroll
      for (int mt = 0; mt < 2; ++mt)
#pragma unroll
        for (int nt = 0; nt < 2; ++nt)
          acc[mt][nt] = __builtin_amdgcn_mfma_f32_32x32x16_bf16(af[mt], bfr[nt], acc[mt][nt], 0, 0, 0);
    }
  }
#pragma unroll
  for (int nt = 0; nt < 2; ++nt) {
    int ng = n0 + nhalf * 64 + nt * 32 + l31;
    float bias = bih[ng] + bhh[ng];
#pragma unroll
    for (int mt = 0; mt < 2; ++mt) {
#pragma unroll
      for (int r = 0; r < 16; ++r) {
        int row = (r & 3) + 8 * (r >> 2) + 4 * khi;
        long long mg = m0 + mhalf * 64 + mt * 32 + row;   // = t*32 + b
        XP[mg * 4096 + ng] = (bf16_t)(acc[mt][nt][r] + bias);
      }
    }
  }
}

// ---------------------------------------------------------------------------
// Kernel 3: persistent LSTM recurrence, sc1-only cross-WG sync (no wbl2/inv).
// 64 WGs x 256 threads; WG owns 16 h-cols (64 gate rows); W_hh slice in regs.
// h exchange: RELAXED agent-scope (sc1 -> LLC) stores; plain cached loads
// (safe: each trace slab's lines are written once via sc1 and read only after
// the flag; no reader cache ever holds them before that).
// Ordering: h stores -> s_waitcnt vmcnt(0) -> __syncthreads -> flag sc1 store.
// ---------------------------------------------------------------------------
__device__ __forceinline__ float sigf(float x) { return 1.0f / (1.0f + __expf(-x)); }
__device__ __forceinline__ float tanhfast(float x) {
  float e = __expf(-2.0f * fabsf(x));
  float t = (1.0f - e) / (1.0f + e);
  return copysignf(t, x);
}

__global__ __launch_bounds__(256, 1) void lstm_rec(
    const bf16_t* __restrict__ Whh_b, const bf16_t* __restrict__ XP,
    const float* __restrict__ c0, float* __restrict__ OUT,
    bf16_t* __restrict__ HTR, int* flags)
{
  const int tid = threadIdx.x;
  const int lane = tid & 63, wave = tid >> 6;
  const int ntile = wave & 1, khalf = wave >> 1;   // 2 N-tiles x 2 K-halves
  const int wg = blockIdx.x;
  const int l31 = lane & 31, khi = lane >> 5;

  // --- preload W_hh fragments into registers ---
  const int nl = ntile * 32 + l31;                          // local gate col
  const int grow = (nl >> 4) * 1024 + wg * 16 + (nl & 15);  // W_hh row
  const int kbase = khalf * 512 + khi * 8;
  bf16x8 wreg[32];
#pragma unroll
  for (int s = 0; s < 32; ++s)
    wreg[s] = *(const bf16x8*)(Whh_b + (long long)grow * 1024 + kbase + s * 16);

  __shared__ float gL[2][32][65];   // [khalf][m][n_local], padded
  __shared__ float cS[32][18];      // c state fp32, padded
  const int m_e = tid >> 3;
  const int jp = (tid & 7) * 2;
  cS[m_e][jp]     = c0[m_e * 1024 + wg * 16 + jp];
  cS[m_e][jp + 1] = c0[m_e * 1024 + wg * 16 + jp + 1];
  __syncthreads();

  // prefetch xp for t=0
  float xp[4][2];
  {
    const bf16_t* xpb = XP + (long long)m_e * 4096 + wg * 16 + jp;
#pragma unroll
    for (int g = 0; g < 4; ++g) {
      bf16x2 v = *(const bf16x2*)(xpb + g * 1024);
      xp[g][0] = (float)v.x; xp[g][1] = (float)v.y;
    }
  }

  for (int t = 0; t < 512; ++t) {
    // wait until every WG has published h_t (relaxed sc1 loads; no cache inv)
    if (tid < 64) {
      while (__hip_atomic_load(&flags[tid * 16], __ATOMIC_RELAXED,
                               __HIP_MEMORY_SCOPE_AGENT) < t) { }
    }
    __syncthreads();

    // gates partial = W_slice . h_t   (plain cached loads of the slab)
    const bf16_t* hrow = HTR + (long long)t * 32768 + (long long)l31 * 1024 + kbase;
    f32x16 acc0 = {}, acc1 = {};
#pragma unroll
    for (int s = 0; s < 16; ++s) {
      bf16x8 a = *(const bf16x8*)(hrow + s * 16);
      acc0 = __builtin_amdgcn_mfma_f32_32x32x16_bf16(a, wreg[s], acc0, 0, 0, 0);
    }
#pragma unroll
    for (int s = 16; s < 32; ++s) {
      bf16x8 a = *(const bf16x8*)(hrow + s * 16);
      acc1 = __builtin_amdgcn_mfma_f32_32x32x16_bf16(a, wreg[s], acc1, 0, 0, 0);
    }
#pragma unroll
    for (int r = 0; r < 16; ++r) {
      int mm = (r & 3) + 8 * (r >> 2) + 4 * khi;
      gL[khalf][mm][nl] = acc0[r] + acc1[r];
    }
    __syncthreads();

    // elementwise LSTM cell for (m_e, jp..jp+1)
    float hv[2];
#pragma unroll
    for (int e = 0; e < 2; ++e) {
      int j = jp + e;
      float ir  = gL[0][m_e][j]      + gL[1][m_e][j]      + xp[0][e];
      float fr  = gL[0][m_e][16 + j] + gL[1][m_e][16 + j] + xp[1][e];
      float gr  = gL[0][m_e][32 + j] + gL[1][m_e][32 + j] + xp[2][e];
      float orr = gL[0][m_e][48 + j] + gL[1][m_e][48 + j] + xp[3][e];
      float iv = sigf(ir), fv = sigf(fr), gv = tanhfast(gr), ov = sigf(orr);
      float c = fv * cS[m_e][j] + iv * gv;
      cS[m_e][j] = c;
      hv[e] = ov * tanhfast(c);
    }
    // publish h (sc1 write-through to LLC), then flag; OUT stays off the path
    {
      bf16x2 h2; h2.x = (bf16_t)hv[0]; h2.y = (bf16_t)hv[1];
      unsigned int u = __builtin_bit_cast(unsigned int, h2);
      unsigned int* dst = (unsigned int*)(HTR + (long long)(t + 1) * 32768 +
                                          (long long)m_e * 1024 + wg * 16 + jp);
      __hip_atomic_store(dst, u, __ATOMIC_RELAXED, __HIP_MEMORY_SCOPE_AGENT);
    }
    asm volatile("s_waitcnt vmcnt(0)" ::: "memory");  // h stores are at LLC
    __syncthreads();                                  // all waves' stores done
    if (tid == 0)
      __hip_atomic_store(&flags[wg * 16], t + 1, __ATOMIC_RELAXED,
                         __HIP_MEMORY_SCOPE_AGENT);

    // --- off the critical path: OUT store + next-step xp prefetch ---
    *(float2*)(OUT + ((long long)m_e * 512 + t) * 1024 + wg * 16 + jp) =
        make_float2(hv[0], hv[1]);
    if (t < 511) {
      const bf16_t* xpb = XP + ((long long)(t + 1) * 32 + m_e) * 4096 + wg * 16 + jp;
#pragma unroll
      for (int g = 0; g < 4; ++g) {
        bf16x2 v = *(const bf16x2*)(xpb + g * 1024);
        xp[g][0] = (float)v.x; xp[g][1] = (float)v.y;
      }
    }
  }
}

// ---------------------------------------------------------------------------
extern "C" void kernel_launch(void* const* d_in, const int* in_sizes, int n_in,
                              void* d_out, int out_size, void* d_ws, size_t ws_size,
                              hipStream_t stream)
{
  const float* x   = (const float*)d_in[0];
  const float* h0  = (const float*)d_in[1];
  const float* c0  = (const float*)d_in[2];
  const float* Wih = (const float*)d_in[3];
  const float* Whh = (const float*)d_in[4];
  const float* bih = (const float*)d_in[5];
  const float* bhh = (const float*)d_in[6];
  float* out = (float*)d_out;

  char* ws = (char*)d_ws;
  bf16_t* xbf   = (bf16_t*)(ws + OFF_XBF);
  bf16_t* wihbf = (bf16_t*)(ws + OFF_WIH);
  bf16_t* whhbf = (bf16_t*)(ws + OFF_WHH);
  bf16_t* xproj = (bf16_t*)(ws + OFF_XPROJ);
  bf16_t* htr   = (bf16_t*)(ws + OFF_HTR);
  int* flags    = (int*)(ws + OFF_FLAGS);

  convert_pack<<<14369, 256, 0, stream>>>(x, h0, Wih, Whh, xbf, wihbf, whhbf, htr, flags);
  xproj_gemm<<<dim3(128, 32), 256, 0, stream>>>(xbf, wihbf, bih, bhh, xproj);
  lstm_rec<<<64, 256, 0, stream>>>(whhbf, xproj, c0, out, htr, flags);
}